// Round 15
// baseline (1778.342 us; speedup 1.0000x reference)
//
#include <hip/hip_runtime.h>
#include <hip/hip_fp16.h>

#define D 64

// ---------------- CSR build ----------------

__global__ __launch_bounds__(256) void hist_kernel(const int* __restrict__ dst,
                                                   int* __restrict__ cnt, int E) {
  int e = blockIdx.x * 256 + threadIdx.x;
  if (e < E) atomicAdd(&cnt[dst[e]], 1);
}

__global__ __launch_bounds__(1024) void scan_partial_kernel(const int* __restrict__ cnt,
                                                            int* __restrict__ bsum, int N) {
  __shared__ int lds[1024];
  int i = blockIdx.x * 1024 + threadIdx.x;
  lds[threadIdx.x] = (i < N) ? cnt[i] : 0;
  __syncthreads();
  for (int off = 512; off > 0; off >>= 1) {
    if (threadIdx.x < off) lds[threadIdx.x] += lds[threadIdx.x + off];
    __syncthreads();
  }
  if (threadIdx.x == 0) bsum[blockIdx.x] = lds[0];
}

// exclusive scan of up to 64 block sums in one wave
__global__ void scan_bsum_kernel(int* __restrict__ bsum, int nb,
                                 int* __restrict__ row_ptr, int N, int E) {
  int tid = threadIdx.x;  // 64 threads
  int o = (tid < nb) ? bsum[tid] : 0;
  int v = o;
  for (int off = 1; off < 64; off <<= 1) {
    int t = __shfl_up(v, off, 64);
    if (tid >= off) v += t;
  }
  if (tid < nb) bsum[tid] = v - o;       // exclusive
  if (tid == 0) row_ptr[N] = E;          // total is always E
}

__global__ __launch_bounds__(1024) void scan_final_kernel(const int* __restrict__ cnt,
                                                          const int* __restrict__ bsum,
                                                          int* __restrict__ row_ptr,
                                                          int* __restrict__ cursor, int N) {
  __shared__ int lds[1024];
  int tid = threadIdx.x;
  int i = blockIdx.x * 1024 + tid;
  int v = (i < N) ? cnt[i] : 0;
  lds[tid] = v;
  __syncthreads();
  for (int off = 1; off < 1024; off <<= 1) {
    int t = (tid >= off) ? lds[tid - off] : 0;
    __syncthreads();
    lds[tid] += t;
    __syncthreads();
  }
  if (i < N) {
    int excl = bsum[blockIdx.x] + lds[tid] - v;
    row_ptr[i] = excl;
    cursor[i] = excl;
  }
}

__global__ __launch_bounds__(256) void scatter_kernel(const int* __restrict__ srcs,
                                                      const int* __restrict__ dst,
                                                      int* __restrict__ cursor,
                                                      int* __restrict__ csr_src, int E) {
  int e = blockIdx.x * 256 + threadIdx.x;
  if (e < E) {
    int p = atomicAdd(&cursor[dst[e]], 1);
    csr_src[p] = srcs[e];
  }
}

// ---------------- node MLP: R = relu(hn@Wm1+bm1) in FP16 only ----------------
// root transform moved into agg (its VALU shadow). BN folded inline; bnS==null -> layer 0.

__global__ __launch_bounds__(256, 4) void node_mlp_kernel(
    const float* __restrict__ hin, const float* __restrict__ bnS, const float* __restrict__ bnSS,
    const float* __restrict__ gammaL, const float* __restrict__ betaL,
    const float* __restrict__ W1, const float* __restrict__ b1,
    __half* __restrict__ Rout, int N) {
  __shared__ float w1[D * D];
  __shared__ float hrow[32][D];
  const int tid = threadIdx.x;
  for (int i = tid; i < D * D; i += 256) w1[i] = W1[i];
  const int c = tid & 63;
  const int w = tid >> 6;
  float sc = 1.f, sh = 0.f;
  if (bnS) {
    float invN = 1.f / (float)N;
    float mu = bnS[c] * invN;
    float var = bnSS[c] * invN - mu * mu;
    float s = gammaL[c] * rsqrtf(var + 1e-5f);
    sc = s;
    sh = betaL[c] - mu * s;
  }
  const float bb1 = b1[c];
  const int ntiles = (N + 31) >> 5;
  for (int t = blockIdx.x; t < ntiles; t += gridDim.x) {
    const int base = t * 32;
    __syncthreads();
#pragma unroll
    for (int j = 0; j < 8; ++j) {
      int r = 4 * j + w;
      int row = base + r;
      float v = (row < N) ? hin[(size_t)row * D + c] : 0.f;
      hrow[r][c] = v * sc + sh;
    }
    __syncthreads();
    float a1[8];
#pragma unroll
    for (int j = 0; j < 8; ++j) a1[j] = bb1;
    for (int k = 0; k < D; k += 4) {
      const float wa = w1[(k + 0) * D + c];
      const float wb = w1[(k + 1) * D + c];
      const float wc = w1[(k + 2) * D + c];
      const float wd = w1[(k + 3) * D + c];
#pragma unroll
      for (int j = 0; j < 8; ++j) {
        const float4 h4 = *(const float4*)&hrow[w * 8 + j][k];
        a1[j] += h4.x * wa + h4.y * wb + h4.z * wc + h4.w * wd;
      }
    }
#pragma unroll
    for (int j = 0; j < 8; ++j) {
      int row = base + w * 8 + j;
      if (row < N) Rout[(size_t)row * D + c] = __float2half(fmaxf(a1[j], 0.f));
    }
  }
}

// ---------------- aggregation + Wm2 matmul + INLINE ROOT TRANSFORM + PReLU + BN ----------
// TWO NODES PER WAVE (round 12, proven). Root matmul hn@Wr runs in the gather-latency
// shadow (independent of gathers; VALUBusy was 21%). hn = BN(h_prev) folded per-lane.

__device__ __forceinline__ float lane_bcast(float v, int lane) {
  return __int_as_float(__builtin_amdgcn_readlane(__float_as_int(v), lane));
}

__global__ __launch_bounds__(256) void agg_kernel(
    const int* __restrict__ row_ptr, const int* __restrict__ csr_src,
    const __half* __restrict__ Rm, const float* __restrict__ hin,
    const float* __restrict__ bnS, const float* __restrict__ bnSS,
    const float* __restrict__ gammaL, const float* __restrict__ betaL,
    const float* __restrict__ W2m, const float* __restrict__ b2m,
    const float* __restrict__ Wrm, const float* __restrict__ brm,
    const float* __restrict__ aconv, float* __restrict__ hout,
    float* __restrict__ bnsum, float* __restrict__ bnsumsq, int N) {
  __shared__ float w2[D * D];
  __shared__ float wr[D * D];
  __shared__ float red[4][D];
  __shared__ float red2[4][D];
  const int tid = threadIdx.x;
  const int c = tid & 63;
  const int w = tid >> 6;
  const int q = c & 15;        // channel quad: channels 4q..4q+3
  const int slot = c >> 4;     // 0..3
  const int half = slot >> 1;  // 0 = node A, 1 = node B
  const int eslot = slot & 1;  // edge sub-slot within the node
  const int l32 = c & 31;      // lane within half
  for (int i = tid; i < D * D; i += 256) { w2[i] = W2m[i]; wr[i] = Wrm[i]; }
  float sc = 1.f, shv = 0.f;
  if (bnS) {
    float invN = 1.f / (float)N;
    float mu = bnS[c] * invN;
    float var = bnSS[c] * invN - mu * mu;
    float s = gammaL[c] * rsqrtf(var + 1e-5f);
    sc = s;
    shv = betaL[c] - mu * s;
  }
  const float alpha = *aconv;
  const float bb = b2m[c];
  const float br_c = brm[c];
  const int NWAVES = gridDim.x * 4;
  float psum = 0.f, psumsq = 0.f;
  __syncthreads();

  const int npairs = (N + 1) >> 1;
  for (int p = blockIdx.x * 4 + w; p < npairs; p += NWAVES) {
    const int nA = 2 * p;
    const int nB = nA + 1;
    const int myn = nA + half;
    int e0 = 0, deg = 0;
    if (myn < N) {
      e0 = row_ptr[myn];
      deg = row_ptr[myn + 1] - e0;
    }
    const int degA = __shfl(deg, 0, 64);
    const int degB = __shfl(deg, 32, 64);
    const int dm = degA > degB ? degA : degB;
    // per-lane BN'd h rows for the root transform (independent of gathers)
    const float hnA = hin[(size_t)nA * D + c] * sc + shv;
    const float hnB = (nB < N) ? hin[(size_t)nB * D + c] * sc + shv : 0.f;
    float acc0 = 0.f, acc1 = 0.f, acc2 = 0.f, acc3 = 0.f;
    for (int base = 0; base < dm; base += 32) {
      const int rem = deg - base;
      const int m_my = rem < 32 ? rem : 32;  // may be <= 0 for the shorter half
      int idxreg = 0;
      if (m_my > 0) idxreg = csr_src[e0 + base + (l32 < m_my ? l32 : m_my - 1)];
      const int itop = (dm - base) < 32 ? (dm - base) : 32;
      for (int kk = 0; kk < itop; kk += 2) {
        const int k = kk + eslot;
        const int sidx = __shfl(idxreg, half * 32 + k, 64);
        if (k < m_my) {
          const uint2 rv = *(const uint2*)(Rm + (size_t)sidx * D + (q << 2));
          const float2 f01 = __half22float2(*(const __half2*)&rv.x);
          const float2 f23 = __half22float2(*(const __half2*)&rv.y);
          acc0 += f01.x;
          acc1 += f01.y;
          acc2 += f23.x;
          acc3 += f23.y;
        }
      }
    }
    // root transform: HR = hn@Wr (+br later) -- scheduled under gather waits
    float rA0 = 0.f, rA1 = 0.f, rB0 = 0.f, rB1 = 0.f;
#pragma unroll
    for (int kk = 0; kk < D; kk += 2) {
      const float wv0 = wr[(kk + 0) * D + c];
      const float wv1 = wr[(kk + 1) * D + c];
      rA0 += lane_bcast(hnA, kk + 0) * wv0;
      rA1 += lane_bcast(hnA, kk + 1) * wv1;
      rB0 += lane_bcast(hnB, kk + 0) * wv0;
      rB1 += lane_bcast(hnB, kk + 1) * wv1;
    }
    // combine the two edge sub-slots within each half (0-15<->16-31, 32-47<->48-63)
    acc0 += __shfl_xor(acc0, 16, 64);
    acc1 += __shfl_xor(acc1, 16, 64);
    acc2 += __shfl_xor(acc2, 16, 64);
    acc3 += __shfl_xor(acc3, 16, 64);
    // matmul both nodes: A's aggregate in lanes 0..15 (quad = lane), B's in 32..47
    float oA0 = 0.f, oA1 = 0.f, oA2 = 0.f, oA3 = 0.f;
    float oB0 = 0.f, oB1 = 0.f, oB2 = 0.f, oB3 = 0.f;
#pragma unroll
    for (int kk = 0; kk < D; kk += 4) {
      const int src = kk >> 2;
      const float wv0 = w2[(kk + 0) * D + c];
      const float wv1 = w2[(kk + 1) * D + c];
      const float wv2 = w2[(kk + 2) * D + c];
      const float wv3 = w2[(kk + 3) * D + c];
      oA0 += lane_bcast(acc0, src) * wv0;
      oA1 += lane_bcast(acc1, src) * wv1;
      oA2 += lane_bcast(acc2, src) * wv2;
      oA3 += lane_bcast(acc3, src) * wv3;
      oB0 += lane_bcast(acc0, 32 + src) * wv0;
      oB1 += lane_bcast(acc1, 32 + src) * wv1;
      oB2 += lane_bcast(acc2, 32 + src) * wv2;
      oB3 += lane_bcast(acc3, 32 + src) * wv3;
    }
    {
      const float o = ((oA0 + oA1) + (oA2 + oA3)) + bb * (float)degA + (rA0 + rA1) + br_c;
      const float h2 = (o >= 0.f) ? o : alpha * o;
      hout[(size_t)nA * D + c] = h2;
      psum += h2;
      psumsq += h2 * h2;
    }
    if (nB < N) {
      const float o = ((oB0 + oB1) + (oB2 + oB3)) + bb * (float)degB + (rB0 + rB1) + br_c;
      const float h2 = (o >= 0.f) ? o : alpha * o;
      hout[(size_t)nB * D + c] = h2;
      psum += h2;
      psumsq += h2 * h2;
    }
  }
  red[w][c] = psum;
  red2[w][c] = psumsq;
  __syncthreads();
  if (w == 0) {
    float s = red[0][c] + red[1][c] + red[2][c] + red[3][c];
    float ss = red2[0][c] + red2[1][c] + red2[2][c] + red2[3][c];
    atomicAdd(&bnsum[c], s);
    atomicAdd(&bnsumsq[c], ss);
  }
}

// ---------------- pooling, stage 1: parallel partial sums into gsum[G][D] ----------------

__global__ __launch_bounds__(256) void pool_partial_kernel(const float* __restrict__ h,
                                                           const int* __restrict__ batch,
                                                           float* __restrict__ gsum, int N) {
  const int c = threadIdx.x & 63;
  const int w = threadIdx.x >> 6;
  const int span = (N + gridDim.x - 1) / gridDim.x;
  const int r0 = blockIdx.x * span;
  const int rend = (r0 + span < N) ? r0 + span : N;
  int curg = -1;
  float acc = 0.f;
  for (int r = r0 + w; r < rend; r += 4) {
    const int g = batch[r];
    const float v = h[(size_t)r * D + c];
    if (g != curg) {
      if (curg >= 0) atomicAdd(&gsum[(size_t)curg * D + c], acc);
      acc = 0.f;
      curg = g;
    }
    acc += v;
  }
  if (curg >= 0) atomicAdd(&gsum[(size_t)curg * D + c], acc);
}

// ---------------- pooling, stage 2: BN-fold + MLP head (tiny) ----------------

__global__ void head_kernel(const float* __restrict__ gsum, const int* __restrict__ batch,
                            const float* __restrict__ bnS, const float* __restrict__ bnSS,
                            const float* __restrict__ gammaL, const float* __restrict__ betaL,
                            const float* __restrict__ Wh1, const float* __restrict__ bh1,
                            const float* __restrict__ Wh2, const float* __restrict__ bh2,
                            const float* __restrict__ ahead, float* __restrict__ out, int N) {
  const int g = blockIdx.x;
  const int j = threadIdx.x;  // 64 threads = 1 wave
  __shared__ float mean[D];
  {
    const int c = j;
    float invN = 1.f / (float)N;
    float mu = bnS[c] * invN;
    float var = bnSS[c] * invN - mu * mu;
    float s = gammaL[c] * rsqrtf(var + 1e-5f);
    float sh = betaL[c] - mu * s;
    int lo = 0, hi = N;
    while (lo < hi) { int mid = (lo + hi) >> 1; if (batch[mid] < g) lo = mid + 1; else hi = mid; }
    int s0 = lo;
    lo = s0; hi = N;
    while (lo < hi) { int mid = (lo + hi) >> 1; if (batch[mid] < g + 1) lo = mid + 1; else hi = mid; }
    float cnt = fmaxf((float)(lo - s0), 1.0f);
    mean[c] = (gsum[(size_t)g * D + c] / cnt) * s + sh;
  }
  __syncthreads();
  float a = bh1[j];
#pragma unroll
  for (int k = 0; k < D; ++k) a += mean[k] * Wh1[k * D + j];
  const float al = *ahead;
  const float v = (a >= 0.f) ? a : al * a;
  float pval = v * Wh2[j];
  for (int off = 32; off > 0; off >>= 1) pval += __shfl_down(pval, off, 64);
  if (j == 0) out[g] = pval + bh2[0];
}

// ---------------- host ----------------

extern "C" void kernel_launch(void* const* d_in, const int* in_sizes, int n_in,
                              void* d_out, int out_size, void* d_ws, size_t ws_size,
                              hipStream_t stream) {
  const float* x = (const float*)d_in[0];
  const int* ei = (const int*)d_in[1];
  const int* batch = (const int*)d_in[2];
  const float* Wm1 = (const float*)d_in[3];
  const float* bm1 = (const float*)d_in[4];
  const float* Wm2 = (const float*)d_in[5];
  const float* bm2 = (const float*)d_in[6];
  const float* Wr = (const float*)d_in[7];
  const float* br = (const float*)d_in[8];
  const float* aconv = (const float*)d_in[9];
  const float* gamma = (const float*)d_in[10];
  const float* beta = (const float*)d_in[11];
  const float* Wh1 = (const float*)d_in[12];
  const float* bh1 = (const float*)d_in[13];
  const float* Wh2 = (const float*)d_in[14];
  const float* bh2 = (const float*)d_in[15];
  const float* ahead = (const float*)d_in[16];

  const int N = in_sizes[0] / D;
  const int E = in_sizes[1] / 2;
  const int L = in_sizes[3] / (D * D);
  const int G = out_size;

  const int* srcs = ei;
  const int* dsts = ei + E;

  char* p = (char*)d_ws;
  auto alloc = [&](size_t bytes) {
    char* r = p;
    p += (bytes + 255) & ~(size_t)255;
    return r;
  };
  // zero-init region is contiguous: row_ptr, cursor, bnsum/bnsumsq, gsum -> ONE memset
  int* row_ptr = (int*)alloc((size_t)(N + 1) * 4);
  int* cursor = (int*)alloc((size_t)N * 4);
  float* bnsum = (float*)alloc((size_t)L * D * 4 * 2);
  float* bnsumsq = bnsum + (size_t)L * D;
  float* gsum = (float*)alloc((size_t)G * D * 4);
  const size_t zero_bytes = (size_t)((char*)(gsum + (size_t)G * D) - (char*)row_ptr);
  int* bsum = (int*)alloc(64 * 4);
  int* csr_src = (int*)alloc((size_t)E * 4);
  __half* Rbuf = (__half*)alloc((size_t)N * D * 2);   // fp16 message table (6.4 MB)
  float* hbuf = (float*)alloc((size_t)N * D * 4);

  hipMemsetAsync(row_ptr, 0, zero_bytes, stream);

  // CSR build
  const int nb = (N + 1023) / 1024;
  hist_kernel<<<(E + 255) / 256, 256, 0, stream>>>(dsts, cursor, E);
  scan_partial_kernel<<<nb, 1024, 0, stream>>>(cursor, bsum, N);
  scan_bsum_kernel<<<1, 64, 0, stream>>>(bsum, nb, row_ptr, N, E);
  scan_final_kernel<<<nb, 1024, 0, stream>>>(cursor, bsum, row_ptr, cursor, N);
  scatter_kernel<<<(E + 255) / 256, 256, 0, stream>>>(srcs, dsts, cursor, csr_src, E);

  const int ntiles = (N + 31) / 32;

  const float* hin = x;
  const float* bnS = nullptr;
  const float* bnSS = nullptr;
  const float* gmL = nullptr;
  const float* btL = nullptr;
  for (int l = 0; l < L; ++l) {
    node_mlp_kernel<<<ntiles, 256, 0, stream>>>(hin, bnS, bnSS, gmL, btL,
                                                Wm1 + (size_t)l * D * D, bm1 + l * D, Rbuf, N);
    agg_kernel<<<2048, 256, 0, stream>>>(row_ptr, csr_src, Rbuf, hin, bnS, bnSS, gmL, btL,
                                         Wm2 + (size_t)l * D * D, bm2 + l * D,
                                         Wr + (size_t)l * D * D, br + l * D, aconv + l,
                                         hbuf, bnsum + l * D, bnsumsq + l * D, N);
    hin = hbuf;
    bnS = bnsum + l * D;
    bnSS = bnsumsq + l * D;
    gmL = gamma + l * D;
    btL = beta + l * D;
  }

  pool_partial_kernel<<<1024, 256, 0, stream>>>(hbuf, batch, gsum, N);
  head_kernel<<<G, 64, 0, stream>>>(gsum, batch, bnS, bnSS, gmL, btL,
                                    Wh1, bh1, Wh2, bh2, ahead, (float*)d_out, N);
}

// Round 16
// 532.469 us; speedup vs baseline: 3.3398x; 3.3398x over previous
//
#include <hip/hip_runtime.h>
#include <hip/hip_fp16.h>

#define D 64

// ---------------- CSR build ----------------

__global__ __launch_bounds__(256) void hist_kernel(const int* __restrict__ dst,
                                                   int* __restrict__ cnt, int E) {
  int e = blockIdx.x * 256 + threadIdx.x;
  if (e < E) atomicAdd(&cnt[dst[e]], 1);
}

__global__ __launch_bounds__(1024) void scan_partial_kernel(const int* __restrict__ cnt,
                                                            int* __restrict__ bsum, int N) {
  __shared__ int lds[1024];
  int i = blockIdx.x * 1024 + threadIdx.x;
  lds[threadIdx.x] = (i < N) ? cnt[i] : 0;
  __syncthreads();
  for (int off = 512; off > 0; off >>= 1) {
    if (threadIdx.x < off) lds[threadIdx.x] += lds[threadIdx.x + off];
    __syncthreads();
  }
  if (threadIdx.x == 0) bsum[blockIdx.x] = lds[0];
}

// exclusive scan of up to 64 block sums in one wave
__global__ void scan_bsum_kernel(int* __restrict__ bsum, int nb,
                                 int* __restrict__ row_ptr, int N, int E) {
  int tid = threadIdx.x;  // 64 threads
  int o = (tid < nb) ? bsum[tid] : 0;
  int v = o;
  for (int off = 1; off < 64; off <<= 1) {
    int t = __shfl_up(v, off, 64);
    if (tid >= off) v += t;
  }
  if (tid < nb) bsum[tid] = v - o;       // exclusive
  if (tid == 0) row_ptr[N] = E;          // total is always E
}

__global__ __launch_bounds__(1024) void scan_final_kernel(const int* __restrict__ cnt,
                                                          const int* __restrict__ bsum,
                                                          int* __restrict__ row_ptr,
                                                          int* __restrict__ cursor, int N) {
  __shared__ int lds[1024];
  int tid = threadIdx.x;
  int i = blockIdx.x * 1024 + tid;
  int v = (i < N) ? cnt[i] : 0;
  lds[tid] = v;
  __syncthreads();
  for (int off = 1; off < 1024; off <<= 1) {
    int t = (tid >= off) ? lds[tid - off] : 0;
    __syncthreads();
    lds[tid] += t;
    __syncthreads();
  }
  if (i < N) {
    int excl = bsum[blockIdx.x] + lds[tid] - v;
    row_ptr[i] = excl;
    cursor[i] = excl;
  }
}

__global__ __launch_bounds__(256) void scatter_kernel(const int* __restrict__ srcs,
                                                      const int* __restrict__ dst,
                                                      int* __restrict__ cursor,
                                                      int* __restrict__ csr_src, int E) {
  int e = blockIdx.x * 256 + threadIdx.x;
  if (e < E) {
    int p = atomicAdd(&cursor[dst[e]], 1);
    csr_src[p] = srcs[e];
  }
}

// ---------------- node MLP: R = relu(h@Wm1+bm1) in FP16 (row-major), HR = h@Wr+br ----------
// applies previous layer's folded BN inline from raw sums; bnS==null -> identity (layer 0)

__global__ __launch_bounds__(256, 4) void node_mlp_kernel(
    const float* __restrict__ hin, const float* __restrict__ bnS, const float* __restrict__ bnSS,
    const float* __restrict__ gammaL, const float* __restrict__ betaL,
    const float* __restrict__ W1, const float* __restrict__ b1,
    const float* __restrict__ W2, const float* __restrict__ b2,
    __half* __restrict__ Rout, float* __restrict__ HRout, int N) {
  __shared__ float2 w12[D * D];  // [k][c] = {W1[k][c], W2[k][c]}
  __shared__ float hrow[32][D];
  const int tid = threadIdx.x;
  for (int i = tid; i < D * D; i += 256) w12[i] = make_float2(W1[i], W2[i]);
  const int c = tid & 63;
  const int w = tid >> 6;
  float sc = 1.f, sh = 0.f;
  if (bnS) {
    float invN = 1.f / (float)N;
    float mu = bnS[c] * invN;
    float var = bnSS[c] * invN - mu * mu;
    float s = gammaL[c] * rsqrtf(var + 1e-5f);
    sc = s;
    sh = betaL[c] - mu * s;
  }
  const float bb1 = b1[c], bb2 = b2[c];
  const int ntiles = (N + 31) >> 5;
  for (int t = blockIdx.x; t < ntiles; t += gridDim.x) {
    const int base = t * 32;
    __syncthreads();
#pragma unroll
    for (int j = 0; j < 8; ++j) {
      int r = 4 * j + w;
      int row = base + r;
      float v = (row < N) ? hin[(size_t)row * D + c] : 0.f;
      hrow[r][c] = v * sc + sh;
    }
    __syncthreads();
    float a1[8], a2[8];
#pragma unroll
    for (int j = 0; j < 8; ++j) { a1[j] = bb1; a2[j] = bb2; }
    for (int k = 0; k < D; k += 4) {
      const float2 wa = w12[(k + 0) * D + c];
      const float2 wb = w12[(k + 1) * D + c];
      const float2 wc = w12[(k + 2) * D + c];
      const float2 wd = w12[(k + 3) * D + c];
#pragma unroll
      for (int j = 0; j < 8; ++j) {
        const float4 h4 = *(const float4*)&hrow[w * 8 + j][k];
        a1[j] += h4.x * wa.x + h4.y * wb.x + h4.z * wc.x + h4.w * wd.x;
        a2[j] += h4.x * wa.y + h4.y * wb.y + h4.z * wc.y + h4.w * wd.y;
      }
    }
#pragma unroll
    for (int j = 0; j < 8; ++j) {
      int row = base + w * 8 + j;
      if (row < N) {
        Rout[(size_t)row * D + c] = __float2half(fmaxf(a1[j], 0.f));
        HRout[(size_t)row * D + c] = a2[j];
      }
    }
  }
}

// ---------------- aggregation + Wm2 + root add + PReLU + BN partial sums ----------------
// TWO NODES PER WAVE (round 12, proven): lanes 0-31 node A, 32-63 node B.

__device__ __forceinline__ float lane_bcast(float v, int lane) {
  return __int_as_float(__builtin_amdgcn_readlane(__float_as_int(v), lane));
}

__global__ __launch_bounds__(256) void agg_kernel(const int* __restrict__ row_ptr,
                                                  const int* __restrict__ csr_src,
                                                  const __half* __restrict__ Rm,
                                                  const float* __restrict__ HRm,
                                                  const float* __restrict__ W2m,
                                                  const float* __restrict__ b2m,
                                                  const float* __restrict__ aconv,
                                                  float* __restrict__ hout,
                                                  float* __restrict__ bnsum,
                                                  float* __restrict__ bnsumsq, int N) {
  __shared__ float w2[D * D];
  __shared__ float red[4][D];
  __shared__ float red2[4][D];
  const int tid = threadIdx.x;
  const int c = tid & 63;
  const int w = tid >> 6;
  const int q = c & 15;        // channel quad: channels 4q..4q+3
  const int slot = c >> 4;     // 0..3
  const int half = slot >> 1;  // 0 = node A, 1 = node B
  const int eslot = slot & 1;  // edge sub-slot within the node
  const int l32 = c & 31;      // lane within half
  for (int i = tid; i < D * D; i += 256) w2[i] = W2m[i];
  const float alpha = *aconv;
  const float bb = b2m[c];
  const int NWAVES = gridDim.x * 4;
  float psum = 0.f, psumsq = 0.f;
  __syncthreads();

  const int npairs = (N + 1) >> 1;
  for (int p = blockIdx.x * 4 + w; p < npairs; p += NWAVES) {
    const int nA = 2 * p;
    const int nB = nA + 1;
    const int myn = nA + half;
    int e0 = 0, deg = 0;
    if (myn < N) {
      e0 = row_ptr[myn];
      deg = row_ptr[myn + 1] - e0;
    }
    const int degA = __shfl(deg, 0, 64);
    const int degB = __shfl(deg, 32, 64);
    const int dm = degA > degB ? degA : degB;
    float acc0 = 0.f, acc1 = 0.f, acc2 = 0.f, acc3 = 0.f;
    for (int base = 0; base < dm; base += 32) {
      const int rem = deg - base;
      const int m_my = rem < 32 ? rem : 32;  // may be <= 0 for the shorter half
      int idxreg = 0;
      if (m_my > 0) idxreg = csr_src[e0 + base + (l32 < m_my ? l32 : m_my - 1)];
      const int itop = (dm - base) < 32 ? (dm - base) : 32;
      for (int kk = 0; kk < itop; kk += 2) {
        const int k = kk + eslot;
        const int sidx = __shfl(idxreg, half * 32 + k, 64);
        if (k < m_my) {
          const uint2 rv = *(const uint2*)(Rm + (size_t)sidx * D + (q << 2));
          const float2 f01 = __half22float2(*(const __half2*)&rv.x);
          const float2 f23 = __half22float2(*(const __half2*)&rv.y);
          acc0 += f01.x;
          acc1 += f01.y;
          acc2 += f23.x;
          acc3 += f23.y;
        }
      }
    }
    // combine the two edge sub-slots within each half (0-15<->16-31, 32-47<->48-63)
    acc0 += __shfl_xor(acc0, 16, 64);
    acc1 += __shfl_xor(acc1, 16, 64);
    acc2 += __shfl_xor(acc2, 16, 64);
    acc3 += __shfl_xor(acc3, 16, 64);
    // matmul both nodes: A's aggregate in lanes 0..15 (quad = lane), B's in 32..47
    float oA0 = 0.f, oA1 = 0.f, oA2 = 0.f, oA3 = 0.f;
    float oB0 = 0.f, oB1 = 0.f, oB2 = 0.f, oB3 = 0.f;
#pragma unroll
    for (int kk = 0; kk < D; kk += 4) {
      const int src = kk >> 2;
      const float wv0 = w2[(kk + 0) * D + c];
      const float wv1 = w2[(kk + 1) * D + c];
      const float wv2 = w2[(kk + 2) * D + c];
      const float wv3 = w2[(kk + 3) * D + c];
      oA0 += lane_bcast(acc0, src) * wv0;
      oA1 += lane_bcast(acc1, src) * wv1;
      oA2 += lane_bcast(acc2, src) * wv2;
      oA3 += lane_bcast(acc3, src) * wv3;
      oB0 += lane_bcast(acc0, 32 + src) * wv0;
      oB1 += lane_bcast(acc1, 32 + src) * wv1;
      oB2 += lane_bcast(acc2, 32 + src) * wv2;
      oB3 += lane_bcast(acc3, 32 + src) * wv3;
    }
    {
      const float o = ((oA0 + oA1) + (oA2 + oA3)) + bb * (float)degA + HRm[(size_t)nA * D + c];
      const float h2 = (o >= 0.f) ? o : alpha * o;
      hout[(size_t)nA * D + c] = h2;
      psum += h2;
      psumsq += h2 * h2;
    }
    if (nB < N) {
      const float o = ((oB0 + oB1) + (oB2 + oB3)) + bb * (float)degB + HRm[(size_t)nB * D + c];
      const float h2 = (o >= 0.f) ? o : alpha * o;
      hout[(size_t)nB * D + c] = h2;
      psum += h2;
      psumsq += h2 * h2;
    }
  }
  red[w][c] = psum;
  red2[w][c] = psumsq;
  __syncthreads();
  if (w == 0) {
    float s = red[0][c] + red[1][c] + red[2][c] + red[3][c];
    float ss = red2[0][c] + red2[1][c] + red2[2][c] + red2[3][c];
    atomicAdd(&bnsum[c], s);
    atomicAdd(&bnsumsq[c], ss);
  }
}

// ---------------- pooling, stage 1: parallel partial sums into gsum[G][D] ----------------
// 1024 blocks over contiguous row spans; sorted batch -> run-accumulate, one wave-coalesced
// atomic flush per graph transition.

__global__ __launch_bounds__(256) void pool_partial_kernel(const float* __restrict__ h,
                                                           const int* __restrict__ batch,
                                                           float* __restrict__ gsum, int N) {
  const int c = threadIdx.x & 63;
  const int w = threadIdx.x >> 6;
  const int span = (N + gridDim.x - 1) / gridDim.x;
  const int r0 = blockIdx.x * span;
  const int rend = (r0 + span < N) ? r0 + span : N;
  int curg = -1;
  float acc = 0.f;
  for (int r = r0 + w; r < rend; r += 4) {
    const int g = batch[r];
    const float v = h[(size_t)r * D + c];
    if (g != curg) {
      if (curg >= 0) atomicAdd(&gsum[(size_t)curg * D + c], acc);
      acc = 0.f;
      curg = g;
    }
    acc += v;
  }
  if (curg >= 0) atomicAdd(&gsum[(size_t)curg * D + c], acc);
}

// ---------------- pooling, stage 2: BN-fold + MLP head (tiny) ----------------

__global__ void head_kernel(const float* __restrict__ gsum, const int* __restrict__ batch,
                            const float* __restrict__ bnS, const float* __restrict__ bnSS,
                            const float* __restrict__ gammaL, const float* __restrict__ betaL,
                            const float* __restrict__ Wh1, const float* __restrict__ bh1,
                            const float* __restrict__ Wh2, const float* __restrict__ bh2,
                            const float* __restrict__ ahead, float* __restrict__ out, int N) {
  const int g = blockIdx.x;
  const int j = threadIdx.x;  // 64 threads = 1 wave
  __shared__ float mean[D];
  {
    const int c = j;
    float invN = 1.f / (float)N;
    float mu = bnS[c] * invN;
    float var = bnSS[c] * invN - mu * mu;
    float s = gammaL[c] * rsqrtf(var + 1e-5f);
    float sh = betaL[c] - mu * s;
    int lo = 0, hi = N;
    while (lo < hi) { int mid = (lo + hi) >> 1; if (batch[mid] < g) lo = mid + 1; else hi = mid; }
    int s0 = lo;
    lo = s0; hi = N;
    while (lo < hi) { int mid = (lo + hi) >> 1; if (batch[mid] < g + 1) lo = mid + 1; else hi = mid; }
    float cnt = fmaxf((float)(lo - s0), 1.0f);
    mean[c] = (gsum[(size_t)g * D + c] / cnt) * s + sh;
  }
  __syncthreads();
  float a = bh1[j];
#pragma unroll
  for (int k = 0; k < D; ++k) a += mean[k] * Wh1[k * D + j];
  const float al = *ahead;
  const float v = (a >= 0.f) ? a : al * a;
  float pval = v * Wh2[j];
  for (int off = 32; off > 0; off >>= 1) pval += __shfl_down(pval, off, 64);
  if (j == 0) out[g] = pval + bh2[0];
}

// ---------------- host ----------------

extern "C" void kernel_launch(void* const* d_in, const int* in_sizes, int n_in,
                              void* d_out, int out_size, void* d_ws, size_t ws_size,
                              hipStream_t stream) {
  const float* x = (const float*)d_in[0];
  const int* ei = (const int*)d_in[1];
  const int* batch = (const int*)d_in[2];
  const float* Wm1 = (const float*)d_in[3];
  const float* bm1 = (const float*)d_in[4];
  const float* Wm2 = (const float*)d_in[5];
  const float* bm2 = (const float*)d_in[6];
  const float* Wr = (const float*)d_in[7];
  const float* br = (const float*)d_in[8];
  const float* aconv = (const float*)d_in[9];
  const float* gamma = (const float*)d_in[10];
  const float* beta = (const float*)d_in[11];
  const float* Wh1 = (const float*)d_in[12];
  const float* bh1 = (const float*)d_in[13];
  const float* Wh2 = (const float*)d_in[14];
  const float* bh2 = (const float*)d_in[15];
  const float* ahead = (const float*)d_in[16];

  const int N = in_sizes[0] / D;
  const int E = in_sizes[1] / 2;
  const int L = in_sizes[3] / (D * D);
  const int G = out_size;

  const int* srcs = ei;
  const int* dsts = ei + E;

  char* p = (char*)d_ws;
  auto alloc = [&](size_t bytes) {
    char* r = p;
    p += (bytes + 255) & ~(size_t)255;
    return r;
  };
  // zero-init region is contiguous: row_ptr, cursor, bnsum/bnsumsq, gsum -> ONE memset
  int* row_ptr = (int*)alloc((size_t)(N + 1) * 4);
  int* cursor = (int*)alloc((size_t)N * 4);
  float* bnsum = (float*)alloc((size_t)L * D * 4 * 2);
  float* bnsumsq = bnsum + (size_t)L * D;
  float* gsum = (float*)alloc((size_t)G * D * 4);
  const size_t zero_bytes = (size_t)((char*)(gsum + (size_t)G * D) - (char*)row_ptr);
  int* bsum = (int*)alloc(64 * 4);
  int* csr_src = (int*)alloc((size_t)E * 4);
  __half* Rbuf = (__half*)alloc((size_t)N * D * 2);   // fp16 message table (6.4 MB)
  float* HRbuf = (float*)alloc((size_t)N * D * 4);
  float* hbuf = (float*)alloc((size_t)N * D * 4);

  hipMemsetAsync(row_ptr, 0, zero_bytes, stream);

  // CSR build
  const int nb = (N + 1023) / 1024;
  hist_kernel<<<(E + 255) / 256, 256, 0, stream>>>(dsts, cursor, E);
  scan_partial_kernel<<<nb, 1024, 0, stream>>>(cursor, bsum, N);
  scan_bsum_kernel<<<1, 64, 0, stream>>>(bsum, nb, row_ptr, N, E);
  scan_final_kernel<<<nb, 1024, 0, stream>>>(cursor, bsum, row_ptr, cursor, N);
  scatter_kernel<<<(E + 255) / 256, 256, 0, stream>>>(srcs, dsts, cursor, csr_src, E);

  const int ntiles = (N + 31) / 32;

  const float* hin = x;
  const float* bnS = nullptr;
  const float* bnSS = nullptr;
  const float* gmL = nullptr;
  const float* btL = nullptr;
  for (int l = 0; l < L; ++l) {
    node_mlp_kernel<<<ntiles, 256, 0, stream>>>(hin, bnS, bnSS, gmL, btL,
                                                Wm1 + (size_t)l * D * D, bm1 + l * D,
                                                Wr + (size_t)l * D * D, br + l * D,
                                                Rbuf, HRbuf, N);
    agg_kernel<<<2048, 256, 0, stream>>>(row_ptr, csr_src, Rbuf, HRbuf,
                                         Wm2 + (size_t)l * D * D, bm2 + l * D, aconv + l,
                                         hbuf, bnsum + l * D, bnsumsq + l * D, N);
    hin = hbuf;
    bnS = bnsum + l * D;
    bnSS = bnsumsq + l * D;
    gmL = gamma + l * D;
    btL = beta + l * D;
  }

  pool_partial_kernel<<<1024, 256, 0, stream>>>(hbuf, batch, gsum, N);
  head_kernel<<<G, 64, 0, stream>>>(gsum, batch, bnS, bnSS, gmL, btL,
                                    Wh1, bh1, Wh2, bh2, ahead, (float*)d_out, N);
}